// Round 4
// baseline (89.470 us; speedup 1.0000x reference)
//
#include <hip/hip_runtime.h>
#include <hip/hip_bf16.h>
#include <math.h>

#define DD 256      // feature dim
#define SS 1024     // seq len
#define BB 8        // batch
#define NN 128      // nodes
#define TOK 16      // tokens per block in scorer
#define NT 8        // nodes per tile in pool

// ---------------- Kernel 1: scorer MLP -> scores (B*S) ----------------
// h = x @ W1 + b1 ; LN(h) ; GELU(erf) ; score = h @ W2 + b2
// 4 waves/block; wave owns 4 tokens; thread owns 4 columns (c0=4*lane).
// K-loop: depth-4 circular register buffers, prefetch distance 3, unroll 4
// so all buffer indices are compile-time (no v_mov rotation, no scratch).
__global__ __launch_bounds__(256) void scorer_kernel(
    const float* __restrict__ doc, const float* __restrict__ W1,
    const float* __restrict__ b1, const float* __restrict__ gamma,
    const float* __restrict__ beta, const float* __restrict__ W2,
    const float* __restrict__ b2, float* __restrict__ scores)
{
    __shared__ float xs[TOK][DD];   // 16 KiB input tile

    const int tid  = threadIdx.x;
    const int wave = tid >> 6, lane = tid & 63;
    const int t0   = blockIdx.x * TOK;
    const int c0   = lane * 4;

    // stage x tile: 1024 float4, 4 per thread, coalesced
    {
        const float4* src = reinterpret_cast<const float4*>(doc + (size_t)t0 * DD);
        float4* dst = reinterpret_cast<float4*>(&xs[0][0]);
#pragma unroll
        for (int r = 0; r < 4; ++r) dst[tid + 256 * r] = src[tid + 256 * r];
    }
    __syncthreads();

    const float* xw = &xs[wave * 4][0];   // this wave's 4 token rows
    const float* w1c = W1 + c0;           // thread's column base

    float4 acc[4];
    {
        const float4 bv = *reinterpret_cast<const float4*>(b1 + c0);
#pragma unroll
        for (int t = 0; t < 4; ++t) acc[t] = bv;
    }

    // circular buffers: 4 groups x (4 W1 rows + 4 token x-vals), all float4
    float4 wb[4][4], xb[4][4];

#define LOADG(G, KG)                                                           \
    do {                                                                       \
        const int _k = (KG) * 4;                                               \
        _Pragma("unroll")                                                      \
        for (int i = 0; i < 4; ++i)                                            \
            wb[(G)][i] = *reinterpret_cast<const float4*>(w1c + (size_t)(_k + i) * DD); \
        _Pragma("unroll")                                                      \
        for (int t = 0; t < 4; ++t)                                            \
            xb[(G)][t] = *reinterpret_cast<const float4*>(xw + (size_t)t * DD + _k);    \
    } while (0)

    LOADG(0, 0);
    LOADG(1, 1);
    LOADG(2, 2);

#pragma unroll 4
    for (int kg = 0; kg < 64; ++kg) {
        const int pg = (kg + 3) & 3;      // buffer to prefetch into
        const int pk = (kg + 3) & 63;     // wrap: last 3 prefetches load k=0..2 (unused, valid)
        LOADG(pg, pk);
        const int g = kg & 3;
#pragma unroll
        for (int t = 0; t < 4; ++t) {
            const float4 xv = xb[g][t];
            acc[t].x = fmaf(xv.x, wb[g][0].x, acc[t].x);
            acc[t].y = fmaf(xv.x, wb[g][0].y, acc[t].y);
            acc[t].z = fmaf(xv.x, wb[g][0].z, acc[t].z);
            acc[t].w = fmaf(xv.x, wb[g][0].w, acc[t].w);
            acc[t].x = fmaf(xv.y, wb[g][1].x, acc[t].x);
            acc[t].y = fmaf(xv.y, wb[g][1].y, acc[t].y);
            acc[t].z = fmaf(xv.y, wb[g][1].z, acc[t].z);
            acc[t].w = fmaf(xv.y, wb[g][1].w, acc[t].w);
            acc[t].x = fmaf(xv.z, wb[g][2].x, acc[t].x);
            acc[t].y = fmaf(xv.z, wb[g][2].y, acc[t].y);
            acc[t].z = fmaf(xv.z, wb[g][2].z, acc[t].z);
            acc[t].w = fmaf(xv.z, wb[g][2].w, acc[t].w);
            acc[t].x = fmaf(xv.w, wb[g][3].x, acc[t].x);
            acc[t].y = fmaf(xv.w, wb[g][3].y, acc[t].y);
            acc[t].z = fmaf(xv.w, wb[g][3].z, acc[t].z);
            acc[t].w = fmaf(xv.w, wb[g][3].w, acc[t].w);
        }
    }
#undef LOADG

    // LayerNorm + GELU + dot(W2) — registers + wave shuffles
    const float4 gm = *reinterpret_cast<const float4*>(gamma + c0);
    const float4 be = *reinterpret_cast<const float4*>(beta + c0);
    const float4 w2 = *reinterpret_cast<const float4*>(W2 + c0);
    const float b2v = b2[0];

#pragma unroll
    for (int t = 0; t < 4; ++t) {
        float s1 = acc[t].x + acc[t].y + acc[t].z + acc[t].w;
        float s2 = acc[t].x * acc[t].x + acc[t].y * acc[t].y
                 + acc[t].z * acc[t].z + acc[t].w * acc[t].w;
#pragma unroll
        for (int off = 32; off > 0; off >>= 1) {
            s1 += __shfl_xor(s1, off, 64);
            s2 += __shfl_xor(s2, off, 64);
        }
        const float mean = s1 * (1.f / DD);
        const float var  = s2 * (1.f / DD) - mean * mean;
        const float inv  = rsqrtf(var + 1e-5f);

        float n0 = (acc[t].x - mean) * inv * gm.x + be.x;
        float n1 = (acc[t].y - mean) * inv * gm.y + be.y;
        float n2 = (acc[t].z - mean) * inv * gm.z + be.z;
        float n3 = (acc[t].w - mean) * inv * gm.w + be.w;
        const float kq = 0.70710678118654752f;
        float g0 = 0.5f * n0 * (1.f + erff(n0 * kq));
        float g1 = 0.5f * n1 * (1.f + erff(n1 * kq));
        float g2 = 0.5f * n2 * (1.f + erff(n2 * kq));
        float g3 = 0.5f * n3 * (1.f + erff(n3 * kq));
        float sc = g0 * w2.x + g1 * w2.y + g2 * w2.z + g3 * w2.w;
#pragma unroll
        for (int off = 32; off > 0; off >>= 1) sc += __shfl_xor(sc, off, 64);
        if (lane == 0) scores[t0 + wave * 4 + t] = sc + b2v;
    }
}

// ---------------- Kernel 2: per-node masked max + 1/Z ----------------
__global__ __launch_bounds__(256) void stats_kernel(
    const float* __restrict__ mapping, const float* __restrict__ scores,
    float* __restrict__ mx_out, float* __restrict__ invz_out)
{
    __shared__ float sc_s[SS];      // 4 KiB
    const int tid = threadIdx.x, wave = tid >> 6, lane = tid & 63;
    const int g0 = blockIdx.x * 4;        // 4 nodes per block, same batch
    const int b  = g0 >> 7;               // 128 nodes per batch

    reinterpret_cast<float4*>(sc_s)[tid] =
        reinterpret_cast<const float4*>(scores + (size_t)b * SS)[tid];
    __syncthreads();

    const int g = g0 + wave;
    const float4* mrow4 = reinterpret_cast<const float4*>(mapping + (size_t)g * SS);
    const float4* sc4   = reinterpret_cast<const float4*>(sc_s);

    float4 mv[4], sv[4];
    float mx = -INFINITY;
#pragma unroll
    for (int q = 0; q < 4; ++q) {
        mv[q] = mrow4[lane + (q << 6)];
        sv[q] = sc4[lane + (q << 6)];
        if (mv[q].x > 0.5f) mx = fmaxf(mx, sv[q].x);
        if (mv[q].y > 0.5f) mx = fmaxf(mx, sv[q].y);
        if (mv[q].z > 0.5f) mx = fmaxf(mx, sv[q].z);
        if (mv[q].w > 0.5f) mx = fmaxf(mx, sv[q].w);
    }
#pragma unroll
    for (int off = 32; off > 0; off >>= 1) mx = fmaxf(mx, __shfl_xor(mx, off, 64));
    float z = 0.f;
#pragma unroll
    for (int q = 0; q < 4; ++q) {
        if (mv[q].x > 0.5f) z += __expf(sv[q].x - mx);
        if (mv[q].y > 0.5f) z += __expf(sv[q].y - mx);
        if (mv[q].z > 0.5f) z += __expf(sv[q].z - mx);
        if (mv[q].w > 0.5f) z += __expf(sv[q].w - mx);
    }
#pragma unroll
    for (int off = 32; off > 0; off >>= 1) z += __shfl_xor(z, off, 64);
    if (lane == 0) {
        mx_out[g]   = mx;
        invz_out[g] = (z > 0.f) ? (1.f / z) : 0.f;
    }
}

// ---------------- Kernel 3: weighted pool over an S-chunk ----------------
// blockIdx = (b*16 + ntile)*SC + c ; partial[n][d] for NT nodes
template <int SC>
__global__ __launch_bounds__(256) void pool_kernel(
    const float* __restrict__ doc, const float* __restrict__ mapping,
    const float* __restrict__ scores, const float* __restrict__ mx_in,
    const float* __restrict__ invz_in, float* __restrict__ part)
{
    constexpr int SCH = SS / SC;
    __shared__ float w_lds[NT][SCH];

    const int blk   = blockIdx.x;
    const int c     = blk % SC;
    const int bt    = blk / SC;
    const int ntile = bt & 15;
    const int b     = bt >> 4;
    const int s0    = c * SCH;
    const int tid = threadIdx.x, wave = tid >> 6, lane = tid & 63;

    // weights for NT nodes over this chunk: 4 waves x 2 nodes, float4 I/O
#pragma unroll
    for (int i = 0; i < 2; ++i) {
        const int nl = wave * 2 + i;
        const int g  = b * NN + ntile * NT + nl;
        const float mx   = mx_in[g];
        const float invz = invz_in[g];
        const float4* mrow4 = reinterpret_cast<const float4*>(mapping + (size_t)g * SS + s0);
        const float4* srow4 = reinterpret_cast<const float4*>(scores + (size_t)b * SS + s0);
        float4* wrow4 = reinterpret_cast<float4*>(&w_lds[nl][0]);
#pragma unroll
        for (int q = 0; q < SCH / 256; ++q) {
            const float4 mp = mrow4[lane + (q << 6)];
            const float4 sv = srow4[lane + (q << 6)];
            float4 e;
            e.x = (mp.x > 0.5f) ? __expf(sv.x - mx) * invz : 0.f;
            e.y = (mp.y > 0.5f) ? __expf(sv.y - mx) * invz : 0.f;
            e.z = (mp.z > 0.5f) ? __expf(sv.z - mx) * invz : 0.f;
            e.w = (mp.w > 0.5f) ? __expf(sv.w - mx) * invz : 0.f;
            wrow4[lane + (q << 6)] = e;
        }
    }
    __syncthreads();

    float acc[NT];
#pragma unroll
    for (int n = 0; n < NT; ++n) acc[n] = 0.f;
    const float* docb = doc + ((size_t)b * SS + s0) * DD;

    // depth-2 prefetch on doc columns
    float d0 = docb[(size_t)0 * DD + tid], d1 = docb[(size_t)1 * DD + tid];
    float d2 = docb[(size_t)2 * DD + tid], d3 = docb[(size_t)3 * DD + tid];
    for (int s4 = 0; s4 < SCH - 4; s4 += 4) {
        const float n0 = docb[(size_t)(s4 + 4) * DD + tid];
        const float n1 = docb[(size_t)(s4 + 5) * DD + tid];
        const float n2 = docb[(size_t)(s4 + 6) * DD + tid];
        const float n3 = docb[(size_t)(s4 + 7) * DD + tid];
#pragma unroll
        for (int n = 0; n < NT; ++n) {
            const float4 wv = *reinterpret_cast<const float4*>(&w_lds[n][s4]);
            acc[n] = fmaf(wv.x, d0, acc[n]);
            acc[n] = fmaf(wv.y, d1, acc[n]);
            acc[n] = fmaf(wv.z, d2, acc[n]);
            acc[n] = fmaf(wv.w, d3, acc[n]);
        }
        d0 = n0; d1 = n1; d2 = n2; d3 = n3;
    }
    {
        const int s4 = SCH - 4;
#pragma unroll
        for (int n = 0; n < NT; ++n) {
            const float4 wv = *reinterpret_cast<const float4*>(&w_lds[n][s4]);
            acc[n] = fmaf(wv.x, d0, acc[n]);
            acc[n] = fmaf(wv.y, d1, acc[n]);
            acc[n] = fmaf(wv.z, d2, acc[n]);
            acc[n] = fmaf(wv.w, d3, acc[n]);
        }
    }

    float* p = part + (size_t)blk * (NT * DD);
#pragma unroll
    for (int n = 0; n < NT; ++n) p[(size_t)n * DD + tid] = acc[n];
}

// ---------------- Kernel 4: reduce SC partials ----------------
__global__ __launch_bounds__(256) void reduce_kernel(
    const float* __restrict__ part, float* __restrict__ out)
{
    const int o = blockIdx.x * 256 + threadIdx.x;  // grid 1024 -> all B*N*D
    const int d = o & 255;
    const int g = o >> 8;          // 0..1023 global node
    const int b = g >> 7;
    const int n = g & 127;
    const int ntile = n >> 3, nl = n & 7;
    const size_t base = ((size_t)(b * 16 + ntile) * 4) * (NT * DD) + (size_t)nl * DD + d;
    float s = 0.f;
#pragma unroll
    for (int c = 0; c < 4; ++c) s += part[base + (size_t)c * (NT * DD)];
    out[o] = s;
}

extern "C" void kernel_launch(void* const* d_in, const int* in_sizes, int n_in,
                              void* d_out, int out_size, void* d_ws, size_t ws_size,
                              hipStream_t stream) {
    const float* doc     = (const float*)d_in[0];  // (B,S,D)
    const float* mapping = (const float*)d_in[1];  // (B,N,S)
    // d_in[2] = nodes_len (unused)
    const float* W1    = (const float*)d_in[3];    // (D,D)
    const float* b1    = (const float*)d_in[4];    // (D)
    const float* gamma = (const float*)d_in[5];    // (D)
    const float* beta  = (const float*)d_in[6];    // (D)
    const float* W2    = (const float*)d_in[7];    // (D,1)
    const float* b2    = (const float*)d_in[8];    // (1)
    float* out = (float*)d_out;                    // (B,N,D)

    float* scores = (float*)d_ws;                   // B*S = 8192 f32 (32 KiB)
    float* mx     = scores + BB * SS;               // 1024 f32
    float* invz   = mx + BB * NN;                   // 1024 f32
    float* part   = invz + BB * NN;                 // SC=4 partials: 4 MiB

    const size_t need = (size_t)(BB * SS + 2 * BB * NN) * 4
                      + (size_t)BB * 16 * 4 * NT * DD * 4;

    scorer_kernel<<<(BB * SS) / TOK, 256, 0, stream>>>(doc, W1, b1, gamma, beta, W2, b2, scores);
    stats_kernel<<<(BB * NN) / 4, 256, 0, stream>>>(mapping, scores, mx, invz);

    if (ws_size >= need) {
        pool_kernel<4><<<BB * 16 * 4, 256, 0, stream>>>(doc, mapping, scores, mx, invz, part);
        reduce_kernel<<<(BB * NN * DD) / 256, 256, 0, stream>>>(part, out);
    } else {
        // fallback: no chunking, write directly to out (layout matches)
        pool_kernel<1><<<BB * 16, 256, 0, stream>>>(doc, mapping, scores, mx, invz, out);
    }
}

// Round 5
// 58.581 us; speedup vs baseline: 1.5273x; 1.5273x over previous
//
#include <hip/hip_runtime.h>
#include <hip/hip_bf16.h>
#include <math.h>

#define DD 256      // feature dim
#define SS 1024     // seq len
#define BB 8        // batch
#define NN 128      // nodes
#define TOK 16      // tokens per block in scorer
#define KC 64       // k-chunk staged in LDS
#define NT 8        // nodes per tile in pool

// ---------------- Kernel 1: scorer MLP -> scores (B*S) ----------------
// h = x @ W1 + b1 ; LN(h) ; GELU(erf) ; score = h @ W2 + b2
// 4 waves/block; wave owns 4 tokens; thread owns 4 columns (c0=4*lane).
// W1 is staged in LDS in k-chunks of 64 rows (64 KiB) so the inner loop is
// pure LDS + FMA; no manual register pipelining (compiler schedules lgkmcnt).
__global__ __launch_bounds__(256) void scorer_kernel(
    const float* __restrict__ doc, const float* __restrict__ W1,
    const float* __restrict__ b1, const float* __restrict__ gamma,
    const float* __restrict__ beta, const float* __restrict__ W2,
    const float* __restrict__ b2, float* __restrict__ scores)
{
    __shared__ float xs[TOK][DD];    // 16 KiB input tile
    __shared__ float w1s[KC][DD];    // 64 KiB W1 k-chunk

    const int tid  = threadIdx.x;
    const int wave = tid >> 6, lane = tid & 63;
    const int t0   = blockIdx.x * TOK;
    const int c0   = lane * 4;

    // stage x tile: 1024 float4, 4 per thread, coalesced
    {
        const float4* src = reinterpret_cast<const float4*>(doc + (size_t)t0 * DD);
        float4* dst = reinterpret_cast<float4*>(&xs[0][0]);
#pragma unroll
        for (int r = 0; r < 4; ++r) dst[tid + 256 * r] = src[tid + 256 * r];
    }

    float4 acc[4];
    {
        const float4 bv = *reinterpret_cast<const float4*>(b1 + c0);
#pragma unroll
        for (int t = 0; t < 4; ++t) acc[t] = bv;
    }

    const float* xw = &xs[wave * 4][0];   // this wave's 4 token rows

    for (int kc = 0; kc < DD / KC; ++kc) {
        // stage W1 chunk [kc*KC .. kc*KC+63][0..255]: 4096 float4, 16/thread
        __syncthreads();   // previous chunk fully consumed (also covers xs writes)
        {
            const float4* wsrc = reinterpret_cast<const float4*>(W1 + (size_t)kc * KC * DD);
            float4* wdst = reinterpret_cast<float4*>(&w1s[0][0]);
#pragma unroll
            for (int r = 0; r < 16; ++r) wdst[tid + 256 * r] = wsrc[tid + 256 * r];
        }
        __syncthreads();

        // compute: 16 k4-iters over this chunk, all operands from LDS
#pragma unroll 4
        for (int k4 = 0; k4 < KC / 4; ++k4) {
            const int kb = k4 * 4;           // row within chunk
            const float4 w0 = *reinterpret_cast<const float4*>(&w1s[kb + 0][c0]);
            const float4 w1 = *reinterpret_cast<const float4*>(&w1s[kb + 1][c0]);
            const float4 w2 = *reinterpret_cast<const float4*>(&w1s[kb + 2][c0]);
            const float4 w3 = *reinterpret_cast<const float4*>(&w1s[kb + 3][c0]);
#pragma unroll
            for (int t = 0; t < 4; ++t) {
                const float4 xv = *reinterpret_cast<const float4*>(xw + (size_t)t * DD + kc * KC + kb);
                acc[t].x = fmaf(xv.x, w0.x, acc[t].x);
                acc[t].y = fmaf(xv.x, w0.y, acc[t].y);
                acc[t].z = fmaf(xv.x, w0.z, acc[t].z);
                acc[t].w = fmaf(xv.x, w0.w, acc[t].w);
                acc[t].x = fmaf(xv.y, w1.x, acc[t].x);
                acc[t].y = fmaf(xv.y, w1.y, acc[t].y);
                acc[t].z = fmaf(xv.y, w1.z, acc[t].z);
                acc[t].w = fmaf(xv.y, w1.w, acc[t].w);
                acc[t].x = fmaf(xv.z, w2.x, acc[t].x);
                acc[t].y = fmaf(xv.z, w2.y, acc[t].y);
                acc[t].z = fmaf(xv.z, w2.z, acc[t].z);
                acc[t].w = fmaf(xv.z, w2.w, acc[t].w);
                acc[t].x = fmaf(xv.w, w3.x, acc[t].x);
                acc[t].y = fmaf(xv.w, w3.y, acc[t].y);
                acc[t].z = fmaf(xv.w, w3.z, acc[t].z);
                acc[t].w = fmaf(xv.w, w3.w, acc[t].w);
            }
        }
    }

    // LayerNorm + GELU + dot(W2) — registers + wave shuffles
    const float4 gm = *reinterpret_cast<const float4*>(gamma + c0);
    const float4 be = *reinterpret_cast<const float4*>(beta + c0);
    const float4 w2v = *reinterpret_cast<const float4*>(W2 + c0);
    const float b2v = b2[0];

#pragma unroll
    for (int t = 0; t < 4; ++t) {
        float s1 = acc[t].x + acc[t].y + acc[t].z + acc[t].w;
        float s2 = acc[t].x * acc[t].x + acc[t].y * acc[t].y
                 + acc[t].z * acc[t].z + acc[t].w * acc[t].w;
#pragma unroll
        for (int off = 32; off > 0; off >>= 1) {
            s1 += __shfl_xor(s1, off, 64);
            s2 += __shfl_xor(s2, off, 64);
        }
        const float mean = s1 * (1.f / DD);
        const float var  = s2 * (1.f / DD) - mean * mean;
        const float inv  = rsqrtf(var + 1e-5f);

        float n0 = (acc[t].x - mean) * inv * gm.x + be.x;
        float n1 = (acc[t].y - mean) * inv * gm.y + be.y;
        float n2 = (acc[t].z - mean) * inv * gm.z + be.z;
        float n3 = (acc[t].w - mean) * inv * gm.w + be.w;
        const float kq = 0.70710678118654752f;
        float g0 = 0.5f * n0 * (1.f + erff(n0 * kq));
        float g1 = 0.5f * n1 * (1.f + erff(n1 * kq));
        float g2 = 0.5f * n2 * (1.f + erff(n2 * kq));
        float g3 = 0.5f * n3 * (1.f + erff(n3 * kq));
        float sc = g0 * w2v.x + g1 * w2v.y + g2 * w2v.z + g3 * w2v.w;
#pragma unroll
        for (int off = 32; off > 0; off >>= 1) sc += __shfl_xor(sc, off, 64);
        if (lane == 0) scores[t0 + wave * 4 + t] = sc + b2v;
    }
}

// ---------------- Kernel 2: per-node masked max + 1/Z ----------------
__global__ __launch_bounds__(256) void stats_kernel(
    const float* __restrict__ mapping, const float* __restrict__ scores,
    float* __restrict__ mx_out, float* __restrict__ invz_out)
{
    __shared__ float sc_s[SS];      // 4 KiB
    const int tid = threadIdx.x, wave = tid >> 6, lane = tid & 63;
    const int g0 = blockIdx.x * 4;        // 4 nodes per block, same batch
    const int b  = g0 >> 7;               // 128 nodes per batch

    reinterpret_cast<float4*>(sc_s)[tid] =
        reinterpret_cast<const float4*>(scores + (size_t)b * SS)[tid];
    __syncthreads();

    const int g = g0 + wave;
    const float4* mrow4 = reinterpret_cast<const float4*>(mapping + (size_t)g * SS);
    const float4* sc4   = reinterpret_cast<const float4*>(sc_s);

    float4 mv[4], sv[4];
    float mx = -INFINITY;
#pragma unroll
    for (int q = 0; q < 4; ++q) {
        mv[q] = mrow4[lane + (q << 6)];
        sv[q] = sc4[lane + (q << 6)];
        if (mv[q].x > 0.5f) mx = fmaxf(mx, sv[q].x);
        if (mv[q].y > 0.5f) mx = fmaxf(mx, sv[q].y);
        if (mv[q].z > 0.5f) mx = fmaxf(mx, sv[q].z);
        if (mv[q].w > 0.5f) mx = fmaxf(mx, sv[q].w);
    }
#pragma unroll
    for (int off = 32; off > 0; off >>= 1) mx = fmaxf(mx, __shfl_xor(mx, off, 64));
    float z = 0.f;
#pragma unroll
    for (int q = 0; q < 4; ++q) {
        if (mv[q].x > 0.5f) z += __expf(sv[q].x - mx);
        if (mv[q].y > 0.5f) z += __expf(sv[q].y - mx);
        if (mv[q].z > 0.5f) z += __expf(sv[q].z - mx);
        if (mv[q].w > 0.5f) z += __expf(sv[q].w - mx);
    }
#pragma unroll
    for (int off = 32; off > 0; off >>= 1) z += __shfl_xor(z, off, 64);
    if (lane == 0) {
        mx_out[g]   = mx;
        invz_out[g] = (z > 0.f) ? (1.f / z) : 0.f;
    }
}

// ---------------- Kernel 3: weighted pool over an S-chunk ----------------
// blockIdx = (b*16 + ntile)*SC + c ; partial[n][d] for NT nodes
template <int SC>
__global__ __launch_bounds__(256) void pool_kernel(
    const float* __restrict__ doc, const float* __restrict__ mapping,
    const float* __restrict__ scores, const float* __restrict__ mx_in,
    const float* __restrict__ invz_in, float* __restrict__ part)
{
    constexpr int SCH = SS / SC;
    __shared__ float w_lds[NT][SCH];

    const int blk   = blockIdx.x;
    const int c     = blk % SC;
    const int bt    = blk / SC;
    const int ntile = bt & 15;
    const int b     = bt >> 4;
    const int s0    = c * SCH;
    const int tid = threadIdx.x, wave = tid >> 6, lane = tid & 63;

    // weights for NT nodes over this chunk: 4 waves x 2 nodes, float4 I/O
#pragma unroll
    for (int i = 0; i < 2; ++i) {
        const int nl = wave * 2 + i;
        const int g  = b * NN + ntile * NT + nl;
        const float mx   = mx_in[g];
        const float invz = invz_in[g];
        const float4* mrow4 = reinterpret_cast<const float4*>(mapping + (size_t)g * SS + s0);
        const float4* srow4 = reinterpret_cast<const float4*>(scores + (size_t)b * SS + s0);
        float4* wrow4 = reinterpret_cast<float4*>(&w_lds[nl][0]);
#pragma unroll
        for (int q = 0; q < SCH / 256; ++q) {
            const float4 mp = mrow4[lane + (q << 6)];
            const float4 sv = srow4[lane + (q << 6)];
            float4 e;
            e.x = (mp.x > 0.5f) ? __expf(sv.x - mx) * invz : 0.f;
            e.y = (mp.y > 0.5f) ? __expf(sv.y - mx) * invz : 0.f;
            e.z = (mp.z > 0.5f) ? __expf(sv.z - mx) * invz : 0.f;
            e.w = (mp.w > 0.5f) ? __expf(sv.w - mx) * invz : 0.f;
            wrow4[lane + (q << 6)] = e;
        }
    }
    __syncthreads();

    float acc[NT];
#pragma unroll
    for (int n = 0; n < NT; ++n) acc[n] = 0.f;
    const float* docb = doc + ((size_t)b * SS + s0) * DD;

    // depth-2 prefetch on doc columns
    float d0 = docb[(size_t)0 * DD + tid], d1 = docb[(size_t)1 * DD + tid];
    float d2 = docb[(size_t)2 * DD + tid], d3 = docb[(size_t)3 * DD + tid];
    for (int s4 = 0; s4 < SCH - 4; s4 += 4) {
        const float n0 = docb[(size_t)(s4 + 4) * DD + tid];
        const float n1 = docb[(size_t)(s4 + 5) * DD + tid];
        const float n2 = docb[(size_t)(s4 + 6) * DD + tid];
        const float n3 = docb[(size_t)(s4 + 7) * DD + tid];
#pragma unroll
        for (int n = 0; n < NT; ++n) {
            const float4 wv = *reinterpret_cast<const float4*>(&w_lds[n][s4]);
            acc[n] = fmaf(wv.x, d0, acc[n]);
            acc[n] = fmaf(wv.y, d1, acc[n]);
            acc[n] = fmaf(wv.z, d2, acc[n]);
            acc[n] = fmaf(wv.w, d3, acc[n]);
        }
        d0 = n0; d1 = n1; d2 = n2; d3 = n3;
    }
    {
        const int s4 = SCH - 4;
#pragma unroll
        for (int n = 0; n < NT; ++n) {
            const float4 wv = *reinterpret_cast<const float4*>(&w_lds[n][s4]);
            acc[n] = fmaf(wv.x, d0, acc[n]);
            acc[n] = fmaf(wv.y, d1, acc[n]);
            acc[n] = fmaf(wv.z, d2, acc[n]);
            acc[n] = fmaf(wv.w, d3, acc[n]);
        }
    }

    float* p = part + (size_t)blk * (NT * DD);
#pragma unroll
    for (int n = 0; n < NT; ++n) p[(size_t)n * DD + tid] = acc[n];
}

// ---------------- Kernel 4: reduce SC partials ----------------
__global__ __launch_bounds__(256) void reduce_kernel(
    const float* __restrict__ part, float* __restrict__ out)
{
    const int o = blockIdx.x * 256 + threadIdx.x;  // grid 1024 -> all B*N*D
    const int d = o & 255;
    const int g = o >> 8;          // 0..1023 global node
    const int b = g >> 7;
    const int n = g & 127;
    const int ntile = n >> 3, nl = n & 7;
    const size_t base = ((size_t)(b * 16 + ntile) * 4) * (NT * DD) + (size_t)nl * DD + d;
    float s = 0.f;
#pragma unroll
    for (int c = 0; c < 4; ++c) s += part[base + (size_t)c * (NT * DD)];
    out[o] = s;
}

extern "C" void kernel_launch(void* const* d_in, const int* in_sizes, int n_in,
                              void* d_out, int out_size, void* d_ws, size_t ws_size,
                              hipStream_t stream) {
    const float* doc     = (const float*)d_in[0];  // (B,S,D)
    const float* mapping = (const float*)d_in[1];  // (B,N,S)
    // d_in[2] = nodes_len (unused)
    const float* W1    = (const float*)d_in[3];    // (D,D)
    const float* b1    = (const float*)d_in[4];    // (D)
    const float* gamma = (const float*)d_in[5];    // (D)
    const float* beta  = (const float*)d_in[6];    // (D)
    const float* W2    = (const float*)d_in[7];    // (D,1)
    const float* b2    = (const float*)d_in[8];    // (1)
    float* out = (float*)d_out;                    // (B,N,D)

    float* scores = (float*)d_ws;                   // B*S = 8192 f32 (32 KiB)
    float* mx     = scores + BB * SS;               // 1024 f32
    float* invz   = mx + BB * NN;                   // 1024 f32
    float* part   = invz + BB * NN;                 // SC=4 partials: 4 MiB

    const size_t need = (size_t)(BB * SS + 2 * BB * NN) * 4
                      + (size_t)BB * 16 * 4 * NT * DD * 4;

    scorer_kernel<<<(BB * SS) / TOK, 256, 0, stream>>>(doc, W1, b1, gamma, beta, W2, b2, scores);
    stats_kernel<<<(BB * NN) / 4, 256, 0, stream>>>(mapping, scores, mx, invz);

    if (ws_size >= need) {
        pool_kernel<4><<<BB * 16 * 4, 256, 0, stream>>>(doc, mapping, scores, mx, invz, part);
        reduce_kernel<<<(BB * NN * DD) / 256, 256, 0, stream>>>(part, out);
    } else {
        // fallback: no chunking, write directly to out (layout matches)
        pool_kernel<1><<<BB * 16, 256, 0, stream>>>(doc, mapping, scores, mx, invz, out);
    }
}

// Round 6
// 57.273 us; speedup vs baseline: 1.5622x; 1.0228x over previous
//
#include <hip/hip_runtime.h>
#include <hip/hip_bf16.h>
#include <math.h>

#define DD 256      // feature dim
#define SS 1024     // seq len
#define BB 8        // batch
#define NN 128      // nodes
#define TOK 16      // tokens per block in scorer
#define KS 2        // K-split factor
#define KH (DD/KS)  // 128 rows per K-half
#define KC 64       // k-chunk for fallback scorer
#define NT 8        // nodes per tile in pool

// ---------------- Kernel 1a: partial GEMM h_part = x[:,k-half] @ W1[k-half,:] ----------------
// grid = 1024: tile = blk>>1 (16 tokens), kq = blk&1 (K-half).
// 4 waves/block; wave owns 4 tokens; thread owns 4 cols (c0=4*lane).
// x staged in LDS (broadcast reads); W1 streamed from L2 per-lane float4.
__global__ __launch_bounds__(256) void scorer_partial_kernel(
    const float* __restrict__ doc, const float* __restrict__ W1,
    float* __restrict__ hpart)
{
    __shared__ float xs[TOK][KH];    // 8 KiB

    const int tid  = threadIdx.x;
    const int wave = tid >> 6, lane = tid & 63;
    const int tile = blockIdx.x >> 1;
    const int kq   = blockIdx.x & 1;
    const int t0   = tile * TOK;
    const int k0   = kq * KH;
    const int c0   = lane * 4;

    // stage x half-tile: 512 float4, 2 per thread
#pragma unroll
    for (int r = 0; r < 2; ++r) {
        const int idx = tid + 256 * r;
        const int t   = idx >> 5;      // 32 float4 per token row
        const int j4  = idx & 31;
        reinterpret_cast<float4*>(&xs[t][0])[j4] =
            *reinterpret_cast<const float4*>(doc + (size_t)(t0 + t) * DD + k0 + j4 * 4);
    }
    __syncthreads();

    float4 acc[4];
#pragma unroll
    for (int t = 0; t < 4; ++t) acc[t] = make_float4(0.f, 0.f, 0.f, 0.f);

    const float* xw  = &xs[wave * 4][0];
    const float* w1c = W1 + (size_t)k0 * DD + c0;

#pragma unroll 4
    for (int k4 = 0; k4 < KH / 4; ++k4) {
        const int kb = k4 * 4;
        const float4 w0 = *reinterpret_cast<const float4*>(w1c + (size_t)(kb + 0) * DD);
        const float4 w1 = *reinterpret_cast<const float4*>(w1c + (size_t)(kb + 1) * DD);
        const float4 w2 = *reinterpret_cast<const float4*>(w1c + (size_t)(kb + 2) * DD);
        const float4 w3 = *reinterpret_cast<const float4*>(w1c + (size_t)(kb + 3) * DD);
#pragma unroll
        for (int t = 0; t < 4; ++t) {
            const float4 xv = *reinterpret_cast<const float4*>(xw + (size_t)t * KH + kb);
            acc[t].x = fmaf(xv.x, w0.x, acc[t].x);
            acc[t].y = fmaf(xv.x, w0.y, acc[t].y);
            acc[t].z = fmaf(xv.x, w0.z, acc[t].z);
            acc[t].w = fmaf(xv.x, w0.w, acc[t].w);
            acc[t].x = fmaf(xv.y, w1.x, acc[t].x);
            acc[t].y = fmaf(xv.y, w1.y, acc[t].y);
            acc[t].z = fmaf(xv.y, w1.z, acc[t].z);
            acc[t].w = fmaf(xv.y, w1.w, acc[t].w);
            acc[t].x = fmaf(xv.z, w2.x, acc[t].x);
            acc[t].y = fmaf(xv.z, w2.y, acc[t].y);
            acc[t].z = fmaf(xv.z, w2.z, acc[t].z);
            acc[t].w = fmaf(xv.z, w2.w, acc[t].w);
            acc[t].x = fmaf(xv.w, w3.x, acc[t].x);
            acc[t].y = fmaf(xv.w, w3.y, acc[t].y);
            acc[t].z = fmaf(xv.w, w3.z, acc[t].z);
            acc[t].w = fmaf(xv.w, w3.w, acc[t].w);
        }
    }

    float* hp = hpart + ((size_t)kq * (BB * SS) + t0) * DD;
#pragma unroll
    for (int t = 0; t < 4; ++t)
        *reinterpret_cast<float4*>(hp + (size_t)(wave * 4 + t) * DD + c0) = acc[t];
}

// ---------------- Kernel 1b: combine K-halves + bias + LN + GELU + W2 dot ----------------
__global__ __launch_bounds__(256) void combine_kernel(
    const float* __restrict__ hpart, const float* __restrict__ b1,
    const float* __restrict__ gamma, const float* __restrict__ beta,
    const float* __restrict__ W2, const float* __restrict__ b2,
    float* __restrict__ scores)
{
    const int tid  = threadIdx.x;
    const int wave = tid >> 6, lane = tid & 63;
    const int t0   = blockIdx.x * TOK;
    const int c0   = lane * 4;

    const float4 bv  = *reinterpret_cast<const float4*>(b1 + c0);
    const float4 gm  = *reinterpret_cast<const float4*>(gamma + c0);
    const float4 be  = *reinterpret_cast<const float4*>(beta + c0);
    const float4 w2v = *reinterpret_cast<const float4*>(W2 + c0);
    const float  b2v = b2[0];

#pragma unroll
    for (int t = 0; t < 4; ++t) {
        const int row = t0 + wave * 4 + t;
        const float4 h0 = *reinterpret_cast<const float4*>(hpart + (size_t)row * DD + c0);
        const float4 h1 = *reinterpret_cast<const float4*>(hpart + ((size_t)(BB * SS) + row) * DD + c0);
        float4 h;
        h.x = h0.x + h1.x + bv.x;
        h.y = h0.y + h1.y + bv.y;
        h.z = h0.z + h1.z + bv.z;
        h.w = h0.w + h1.w + bv.w;

        float s1 = h.x + h.y + h.z + h.w;
        float s2 = h.x * h.x + h.y * h.y + h.z * h.z + h.w * h.w;
#pragma unroll
        for (int off = 32; off > 0; off >>= 1) {
            s1 += __shfl_xor(s1, off, 64);
            s2 += __shfl_xor(s2, off, 64);
        }
        const float mean = s1 * (1.f / DD);
        const float var  = s2 * (1.f / DD) - mean * mean;
        const float inv  = rsqrtf(var + 1e-5f);

        const float n0 = (h.x - mean) * inv * gm.x + be.x;
        const float n1 = (h.y - mean) * inv * gm.y + be.y;
        const float n2 = (h.z - mean) * inv * gm.z + be.z;
        const float n3 = (h.w - mean) * inv * gm.w + be.w;
        const float kq = 0.70710678118654752f;
        const float g0 = 0.5f * n0 * (1.f + erff(n0 * kq));
        const float g1 = 0.5f * n1 * (1.f + erff(n1 * kq));
        const float g2 = 0.5f * n2 * (1.f + erff(n2 * kq));
        const float g3 = 0.5f * n3 * (1.f + erff(n3 * kq));
        float sc = g0 * w2v.x + g1 * w2v.y + g2 * w2v.z + g3 * w2v.w;
#pragma unroll
        for (int off = 32; off > 0; off >>= 1) sc += __shfl_xor(sc, off, 64);
        if (lane == 0) scores[row] = sc + b2v;
    }
}

// ---------------- Fallback monolithic scorer (only if ws too small) ----------------
__global__ __launch_bounds__(256) void scorer_kernel(
    const float* __restrict__ doc, const float* __restrict__ W1,
    const float* __restrict__ b1, const float* __restrict__ gamma,
    const float* __restrict__ beta, const float* __restrict__ W2,
    const float* __restrict__ b2, float* __restrict__ scores)
{
    __shared__ float xs[TOK][DD];
    __shared__ float w1s[KC][DD];

    const int tid  = threadIdx.x;
    const int wave = tid >> 6, lane = tid & 63;
    const int t0   = blockIdx.x * TOK;
    const int c0   = lane * 4;

    {
        const float4* src = reinterpret_cast<const float4*>(doc + (size_t)t0 * DD);
        float4* dst = reinterpret_cast<float4*>(&xs[0][0]);
#pragma unroll
        for (int r = 0; r < 4; ++r) dst[tid + 256 * r] = src[tid + 256 * r];
    }

    float4 acc[4];
    {
        const float4 bv = *reinterpret_cast<const float4*>(b1 + c0);
#pragma unroll
        for (int t = 0; t < 4; ++t) acc[t] = bv;
    }
    const float* xw = &xs[wave * 4][0];

    for (int kc = 0; kc < DD / KC; ++kc) {
        __syncthreads();
        {
            const float4* wsrc = reinterpret_cast<const float4*>(W1 + (size_t)kc * KC * DD);
            float4* wdst = reinterpret_cast<float4*>(&w1s[0][0]);
#pragma unroll
            for (int r = 0; r < 16; ++r) wdst[tid + 256 * r] = wsrc[tid + 256 * r];
        }
        __syncthreads();
#pragma unroll 4
        for (int k4 = 0; k4 < KC / 4; ++k4) {
            const int kb = k4 * 4;
            const float4 w0 = *reinterpret_cast<const float4*>(&w1s[kb + 0][c0]);
            const float4 w1 = *reinterpret_cast<const float4*>(&w1s[kb + 1][c0]);
            const float4 w2 = *reinterpret_cast<const float4*>(&w1s[kb + 2][c0]);
            const float4 w3 = *reinterpret_cast<const float4*>(&w1s[kb + 3][c0]);
#pragma unroll
            for (int t = 0; t < 4; ++t) {
                const float4 xv = *reinterpret_cast<const float4*>(xw + (size_t)t * DD + kc * KC + kb);
                acc[t].x = fmaf(xv.x, w0.x, acc[t].x);
                acc[t].y = fmaf(xv.x, w0.y, acc[t].y);
                acc[t].z = fmaf(xv.x, w0.z, acc[t].z);
                acc[t].w = fmaf(xv.x, w0.w, acc[t].w);
                acc[t].x = fmaf(xv.y, w1.x, acc[t].x);
                acc[t].y = fmaf(xv.y, w1.y, acc[t].y);
                acc[t].z = fmaf(xv.y, w1.z, acc[t].z);
                acc[t].w = fmaf(xv.y, w1.w, acc[t].w);
                acc[t].x = fmaf(xv.z, w2.x, acc[t].x);
                acc[t].y = fmaf(xv.z, w2.y, acc[t].y);
                acc[t].z = fmaf(xv.z, w2.z, acc[t].z);
                acc[t].w = fmaf(xv.z, w2.w, acc[t].w);
                acc[t].x = fmaf(xv.w, w3.x, acc[t].x);
                acc[t].y = fmaf(xv.w, w3.y, acc[t].y);
                acc[t].z = fmaf(xv.w, w3.z, acc[t].z);
                acc[t].w = fmaf(xv.w, w3.w, acc[t].w);
            }
        }
    }

    const float4 gm = *reinterpret_cast<const float4*>(gamma + c0);
    const float4 be = *reinterpret_cast<const float4*>(beta + c0);
    const float4 w2v = *reinterpret_cast<const float4*>(W2 + c0);
    const float b2v = b2[0];

#pragma unroll
    for (int t = 0; t < 4; ++t) {
        float s1 = acc[t].x + acc[t].y + acc[t].z + acc[t].w;
        float s2 = acc[t].x * acc[t].x + acc[t].y * acc[t].y
                 + acc[t].z * acc[t].z + acc[t].w * acc[t].w;
#pragma unroll
        for (int off = 32; off > 0; off >>= 1) {
            s1 += __shfl_xor(s1, off, 64);
            s2 += __shfl_xor(s2, off, 64);
        }
        const float mean = s1 * (1.f / DD);
        const float var  = s2 * (1.f / DD) - mean * mean;
        const float inv  = rsqrtf(var + 1e-5f);
        float n0 = (acc[t].x - mean) * inv * gm.x + be.x;
        float n1 = (acc[t].y - mean) * inv * gm.y + be.y;
        float n2 = (acc[t].z - mean) * inv * gm.z + be.z;
        float n3 = (acc[t].w - mean) * inv * gm.w + be.w;
        const float kq = 0.70710678118654752f;
        float g0 = 0.5f * n0 * (1.f + erff(n0 * kq));
        float g1 = 0.5f * n1 * (1.f + erff(n1 * kq));
        float g2 = 0.5f * n2 * (1.f + erff(n2 * kq));
        float g3 = 0.5f * n3 * (1.f + erff(n3 * kq));
        float sc = g0 * w2v.x + g1 * w2v.y + g2 * w2v.z + g3 * w2v.w;
#pragma unroll
        for (int off = 32; off > 0; off >>= 1) sc += __shfl_xor(sc, off, 64);
        if (lane == 0) scores[t0 + wave * 4 + t] = sc + b2v;
    }
}

// ---------------- Kernel 2: per-node masked max + 1/Z ----------------
__global__ __launch_bounds__(256) void stats_kernel(
    const float* __restrict__ mapping, const float* __restrict__ scores,
    float* __restrict__ mx_out, float* __restrict__ invz_out)
{
    __shared__ float sc_s[SS];
    const int tid = threadIdx.x, wave = tid >> 6, lane = tid & 63;
    const int g0 = blockIdx.x * 4;
    const int b  = g0 >> 7;

    reinterpret_cast<float4*>(sc_s)[tid] =
        reinterpret_cast<const float4*>(scores + (size_t)b * SS)[tid];
    __syncthreads();

    const int g = g0 + wave;
    const float4* mrow4 = reinterpret_cast<const float4*>(mapping + (size_t)g * SS);
    const float4* sc4   = reinterpret_cast<const float4*>(sc_s);

    float4 mv[4], sv[4];
    float mx = -INFINITY;
#pragma unroll
    for (int q = 0; q < 4; ++q) {
        mv[q] = mrow4[lane + (q << 6)];
        sv[q] = sc4[lane + (q << 6)];
        if (mv[q].x > 0.5f) mx = fmaxf(mx, sv[q].x);
        if (mv[q].y > 0.5f) mx = fmaxf(mx, sv[q].y);
        if (mv[q].z > 0.5f) mx = fmaxf(mx, sv[q].z);
        if (mv[q].w > 0.5f) mx = fmaxf(mx, sv[q].w);
    }
#pragma unroll
    for (int off = 32; off > 0; off >>= 1) mx = fmaxf(mx, __shfl_xor(mx, off, 64));
    float z = 0.f;
#pragma unroll
    for (int q = 0; q < 4; ++q) {
        if (mv[q].x > 0.5f) z += __expf(sv[q].x - mx);
        if (mv[q].y > 0.5f) z += __expf(sv[q].y - mx);
        if (mv[q].z > 0.5f) z += __expf(sv[q].z - mx);
        if (mv[q].w > 0.5f) z += __expf(sv[q].w - mx);
    }
#pragma unroll
    for (int off = 32; off > 0; off >>= 1) z += __shfl_xor(z, off, 64);
    if (lane == 0) {
        mx_out[g]   = mx;
        invz_out[g] = (z > 0.f) ? (1.f / z) : 0.f;
    }
}

// ---------------- Kernel 3: weighted pool over an S-chunk ----------------
// blockIdx = (b*16 + ntile)*SC + c ; partial[n][d] for NT nodes
template <int SC>
__global__ __launch_bounds__(256) void pool_kernel(
    const float* __restrict__ doc, const float* __restrict__ mapping,
    const float* __restrict__ scores, const float* __restrict__ mx_in,
    const float* __restrict__ invz_in, float* __restrict__ part)
{
    constexpr int SCH = SS / SC;
    __shared__ float w_lds[NT][SCH];

    const int blk   = blockIdx.x;
    const int c     = blk % SC;
    const int bt    = blk / SC;
    const int ntile = bt & 15;
    const int b     = bt >> 4;
    const int s0    = c * SCH;
    const int tid = threadIdx.x, wave = tid >> 6, lane = tid & 63;

    // weights: each wave handles 2 nodes; lane>>5 selects node, lane&31 the float4
    {
        const int nl = wave * 2 + (lane >> 5);
        const int g  = b * NN + ntile * NT + nl;
        const float mx   = mx_in[g];
        const float invz = invz_in[g];
        const float4* mrow4 = reinterpret_cast<const float4*>(mapping + (size_t)g * SS + s0);
        const float4* srow4 = reinterpret_cast<const float4*>(scores + (size_t)b * SS + s0);
        float4* wrow4 = reinterpret_cast<float4*>(&w_lds[nl][0]);
        const int idx0 = lane & 31;
#pragma unroll
        for (int q = 0; q < SCH / 128; ++q) {
            const int idx = idx0 + 32 * q;
            const float4 mp = mrow4[idx];
            const float4 sv = srow4[idx];
            float4 e;
            e.x = (mp.x > 0.5f) ? __expf(sv.x - mx) * invz : 0.f;
            e.y = (mp.y > 0.5f) ? __expf(sv.y - mx) * invz : 0.f;
            e.z = (mp.z > 0.5f) ? __expf(sv.z - mx) * invz : 0.f;
            e.w = (mp.w > 0.5f) ? __expf(sv.w - mx) * invz : 0.f;
            wrow4[idx] = e;
        }
    }
    __syncthreads();

    float acc[NT];
#pragma unroll
    for (int n = 0; n < NT; ++n) acc[n] = 0.f;
    const float* docb = doc + ((size_t)b * SS + s0) * DD;

    float d0 = docb[(size_t)0 * DD + tid], d1 = docb[(size_t)1 * DD + tid];
    float d2 = docb[(size_t)2 * DD + tid], d3 = docb[(size_t)3 * DD + tid];
    for (int s4 = 0; s4 < SCH - 4; s4 += 4) {
        const float n0 = docb[(size_t)(s4 + 4) * DD + tid];
        const float n1 = docb[(size_t)(s4 + 5) * DD + tid];
        const float n2 = docb[(size_t)(s4 + 6) * DD + tid];
        const float n3 = docb[(size_t)(s4 + 7) * DD + tid];
#pragma unroll
        for (int n = 0; n < NT; ++n) {
            const float4 wv = *reinterpret_cast<const float4*>(&w_lds[n][s4]);
            acc[n] = fmaf(wv.x, d0, acc[n]);
            acc[n] = fmaf(wv.y, d1, acc[n]);
            acc[n] = fmaf(wv.z, d2, acc[n]);
            acc[n] = fmaf(wv.w, d3, acc[n]);
        }
        d0 = n0; d1 = n1; d2 = n2; d3 = n3;
    }
    {
        const int s4 = SCH - 4;
#pragma unroll
        for (int n = 0; n < NT; ++n) {
            const float4 wv = *reinterpret_cast<const float4*>(&w_lds[n][s4]);
            acc[n] = fmaf(wv.x, d0, acc[n]);
            acc[n] = fmaf(wv.y, d1, acc[n]);
            acc[n] = fmaf(wv.z, d2, acc[n]);
            acc[n] = fmaf(wv.w, d3, acc[n]);
        }
    }

    float* p = part + (size_t)blk * (NT * DD);
#pragma unroll
    for (int n = 0; n < NT; ++n) p[(size_t)n * DD + tid] = acc[n];
}

// ---------------- Kernel 4: reduce SC=8 partials ----------------
__global__ __launch_bounds__(256) void reduce_kernel(
    const float* __restrict__ part, float* __restrict__ out)
{
    const int o = blockIdx.x * 256 + threadIdx.x;
    const int d = o & 255;
    const int g = o >> 8;
    const int b = g >> 7;
    const int n = g & 127;
    const int ntile = n >> 3, nl = n & 7;
    const size_t base = ((size_t)(b * 16 + ntile) * 8) * (NT * DD) + (size_t)nl * DD + d;
    float s = 0.f;
#pragma unroll
    for (int c = 0; c < 8; ++c) s += part[base + (size_t)c * (NT * DD)];
    out[o] = s;
}

extern "C" void kernel_launch(void* const* d_in, const int* in_sizes, int n_in,
                              void* d_out, int out_size, void* d_ws, size_t ws_size,
                              hipStream_t stream) {
    const float* doc     = (const float*)d_in[0];  // (B,S,D)
    const float* mapping = (const float*)d_in[1];  // (B,N,S)
    // d_in[2] = nodes_len (unused)
    const float* W1    = (const float*)d_in[3];    // (D,D)
    const float* b1    = (const float*)d_in[4];    // (D)
    const float* gamma = (const float*)d_in[5];    // (D)
    const float* beta  = (const float*)d_in[6];    // (D)
    const float* W2    = (const float*)d_in[7];    // (D,1)
    const float* b2    = (const float*)d_in[8];    // (1)
    float* out = (float*)d_out;                    // (B,N,D)

    float* scores = (float*)d_ws;                   // B*S f32
    float* mx     = scores + BB * SS;               // B*N f32
    float* invz   = mx + BB * NN;                   // B*N f32
    float* hpart  = invz + BB * NN;                 // KS*B*S*D f32 (16 MiB)
    float* part   = hpart + (size_t)KS * BB * SS * DD;  // 8*B*16*NT*D f32 (8 MiB)

    const size_t need = ((size_t)(BB * SS + 2 * BB * NN)
                      + (size_t)KS * BB * SS * DD
                      + (size_t)BB * 16 * 8 * NT * DD) * 4;

    if (ws_size >= need) {
        scorer_partial_kernel<<<(BB * SS / TOK) * KS, 256, 0, stream>>>(doc, W1, hpart);
        combine_kernel<<<BB * SS / TOK, 256, 0, stream>>>(hpart, b1, gamma, beta, W2, b2, scores);
        stats_kernel<<<(BB * NN) / 4, 256, 0, stream>>>(mapping, scores, mx, invz);
        pool_kernel<8><<<BB * 16 * 8, 256, 0, stream>>>(doc, mapping, scores, mx, invz, part);
        reduce_kernel<<<(BB * NN * DD) / 256, 256, 0, stream>>>(part, out);
    } else {
        scorer_kernel<<<BB * SS / TOK, 256, 0, stream>>>(doc, W1, b1, gamma, beta, W2, b2, scores);
        stats_kernel<<<(BB * NN) / 4, 256, 0, stream>>>(mapping, scores, mx, invz);
        pool_kernel<1><<<BB * 16, 256, 0, stream>>>(doc, mapping, scores, mx, invz, out);
    }
}